// Round 3
// baseline (381.951 us; speedup 1.0000x reference)
//
#include <hip/hip_runtime.h>
#include <cstddef>

// ---------------------------------------------------------------------------
// NCHL on MI355X. Forward: split-bf16 3-product MFMA GEMMs (no fp32 MFMA on
// CDNA4). a = ahi + alo (bf16 truncation split), product uses
// ahi*bhi + ahi*blo + alo*bhi  -> ~2^-16 relative accuracy, fp32 accum.
// All layers run 128x128-tile GEMMs with split-K so grid == 256 blocks (1/CU).
// Partials reduced (+tanh) by a streaming kernel that also emits the split
// bf16 form of h for the next layer's A operand. Hebbian updates: streaming.
// Scratch: par/xsplit/hsplit live inside the nW2 output slice (dead before
// nW2 is written). d_ws holds only the 200 KB node-param vectors.
// ---------------------------------------------------------------------------

typedef __attribute__((ext_vector_type(8)))  short short8;   // 8 bf16 (4 VGPR)
typedef __attribute__((ext_vector_type(16))) float f32x16;   // 32x32 acc

__device__ __forceinline__ uint  as_u(float f) { return __float_as_uint(f); }
__device__ __forceinline__ float as_f(uint u)  { return __uint_as_float(u); }
__device__ __forceinline__ float4 ld4(const float* p) { return *(const float4*)p; }

// truncation split of (f0,f1) -> packed hi u32 (f0 in low half) + packed lo.
// hi = trunc-bf16(f), lo = trunc-bf16(f - hi); |f - hi - lo| <= 2^-16 |f|.
__device__ __forceinline__ void split2(float f0, float f1, uint& hp, uint& lp) {
    uint u0 = as_u(f0), u1 = as_u(f1);
    uint h0 = u0 & 0xffff0000u, h1 = u1 & 0xffff0000u;
    float l0 = f0 - as_f(h0), l1 = f1 - as_f(h1);
    hp = h1 | (h0 >> 16);
    lp = (as_u(l1) & 0xffff0000u) | (as_u(l0) >> 16);
}

// ---------------------------------------------------------------------------
// GEMM: par[z][m,n] = sum_{k in chunk z} A[m,k] * W[n,k]
// A presplit (Ahi/Alo bf16 bit arrays, row-major [M][K]); W fp32 [N][K].
// Block: 128(M) x 128(N), 4 waves, each wave one 64x64 (2x2 of 32x32 frags).
// BK=64. LDS: 4 regions x 128rows x 64 bf16 = exactly 64 KB, XOR-swizzled.
// ---------------------------------------------------------------------------
#define BKT 64
#define REG_AHI 0
#define REG_ALO 16384
#define REG_BHI 32768
#define REG_BLO 49152

// byte offset inside a region; kbyte is a multiple of 16
__device__ __forceinline__ int swz(int row, int kbyte) {
    return row * 128 + (kbyte ^ ((row & 7) << 4));
}

__global__ __launch_bounds__(256, 1)
void gemm_split(const ushort* __restrict__ Ahi, const ushort* __restrict__ Alo,
                const float* __restrict__ W, float* __restrict__ par,
                int N, int K, int kchunk) {
    __shared__ uint4 lds4[4096];                 // 64 KB
    char* lds = (char*)lds4;

    const int tid = threadIdx.x;
    const int l   = tid & 63;
    const int wid = tid >> 6;
    const int wr  = wid >> 1, wc = wid & 1;      // 2x2 wave grid of 64x64
    const int m0  = blockIdx.y * 128;
    const int n0  = blockIdx.x * 128;
    const int kb0 = blockIdx.z * kchunk;
    const int T   = kchunk / BKT;

    // B staging: thread covers W row (n0+br), k-halfrow bk..bk+31 (8 float4)
    const int br = tid >> 1;
    const int bk = (tid & 1) * 32;

    uint4  aRegH[4], aRegL[4];
    float4 bReg[8];

    auto loadTile = [&](int t) {
        const int kb = kb0 + t * BKT;
#pragma unroll
        for (int i = 0; i < 4; ++i) {            // A: 1024 16B-chunks/half
            int c = tid + 256 * i;
            int row = c >> 3, ko = (c & 7) * 8;
            size_t g = (size_t)(m0 + row) * K + kb + ko;
            aRegH[i] = *(const uint4*)(Ahi + g);
            aRegL[i] = *(const uint4*)(Alo + g);
        }
        const float* wp = W + (size_t)(n0 + br) * K + kb + bk;
#pragma unroll
        for (int i = 0; i < 8; ++i) bReg[i] = ld4(wp + 4 * i);
    };

    auto writeTile = [&]() {
#pragma unroll
        for (int i = 0; i < 4; ++i) {
            int c = tid + 256 * i;
            int row = c >> 3, kby = (c & 7) * 16;
            *(uint4*)(lds + REG_AHI + swz(row, kby)) = aRegH[i];
            *(uint4*)(lds + REG_ALO + swz(row, kby)) = aRegL[i];
        }
#pragma unroll
        for (int i = 0; i < 4; ++i) {            // convert 8 f32 -> 8+8 bf16
            float4 fa = bReg[2 * i], fb = bReg[2 * i + 1];
            uint4 hp, lp;
            split2(fa.x, fa.y, hp.x, lp.x);
            split2(fa.z, fa.w, hp.y, lp.y);
            split2(fb.x, fb.y, hp.z, lp.z);
            split2(fb.z, fb.w, hp.w, lp.w);
            int kby = (bk + 8 * i) * 2;
            *(uint4*)(lds + REG_BHI + swz(br, kby)) = hp;
            *(uint4*)(lds + REG_BLO + swz(br, kby)) = lp;
        }
    };

    f32x16 acc[2][2] = {};

    const int arow = wr * 64 + (l & 31);         // A-tile row of this lane
    const int brow = wc * 64 + (l & 31);         // B-tile row (= output col)
    const int kfr  = 16 * (l >> 5);              // lane-half k byte offset

    loadTile(0);
    for (int t = 0; t < T; ++t) {
        __syncthreads();                          // readers of prev tile done
        writeTile();
        __syncthreads();
        if (t + 1 < T) loadTile(t + 1);          // overlap with MFMA phase
#pragma unroll
        for (int kk = 0; kk < 4; ++kk) {         // 4 x K=16 steps
            const int kby = kk * 32 + kfr;
            short8 ah0 = *(const short8*)(lds + REG_AHI + swz(arow,      kby));
            short8 ah1 = *(const short8*)(lds + REG_AHI + swz(arow + 32, kby));
            short8 al0 = *(const short8*)(lds + REG_ALO + swz(arow,      kby));
            short8 al1 = *(const short8*)(lds + REG_ALO + swz(arow + 32, kby));
            short8 bh0 = *(const short8*)(lds + REG_BHI + swz(brow,      kby));
            short8 bh1 = *(const short8*)(lds + REG_BHI + swz(brow + 32, kby));
            short8 bl0 = *(const short8*)(lds + REG_BLO + swz(brow,      kby));
            short8 bl1 = *(const short8*)(lds + REG_BLO + swz(brow + 32, kby));
            acc[0][0] = __builtin_amdgcn_mfma_f32_32x32x16_bf16(ah0, bh0, acc[0][0], 0, 0, 0);
            acc[0][1] = __builtin_amdgcn_mfma_f32_32x32x16_bf16(ah0, bh1, acc[0][1], 0, 0, 0);
            acc[1][0] = __builtin_amdgcn_mfma_f32_32x32x16_bf16(ah1, bh0, acc[1][0], 0, 0, 0);
            acc[1][1] = __builtin_amdgcn_mfma_f32_32x32x16_bf16(ah1, bh1, acc[1][1], 0, 0, 0);
            acc[0][0] = __builtin_amdgcn_mfma_f32_32x32x16_bf16(ah0, bl0, acc[0][0], 0, 0, 0);
            acc[0][1] = __builtin_amdgcn_mfma_f32_32x32x16_bf16(ah0, bl1, acc[0][1], 0, 0, 0);
            acc[1][0] = __builtin_amdgcn_mfma_f32_32x32x16_bf16(ah1, bl0, acc[1][0], 0, 0, 0);
            acc[1][1] = __builtin_amdgcn_mfma_f32_32x32x16_bf16(ah1, bl1, acc[1][1], 0, 0, 0);
            acc[0][0] = __builtin_amdgcn_mfma_f32_32x32x16_bf16(al0, bh0, acc[0][0], 0, 0, 0);
            acc[0][1] = __builtin_amdgcn_mfma_f32_32x32x16_bf16(al0, bh1, acc[0][1], 0, 0, 0);
            acc[1][0] = __builtin_amdgcn_mfma_f32_32x32x16_bf16(al1, bh0, acc[1][0], 0, 0, 0);
            acc[1][1] = __builtin_amdgcn_mfma_f32_32x32x16_bf16(al1, bh1, acc[1][1], 0, 0, 0);
        }
    }

    // epilogue: C/D layout col=lane&31, row=(q&3)+8*(q>>2)+4*(lane>>5)
    float* slice = par + (size_t)blockIdx.z * 256 * N;
#pragma unroll
    for (int mm = 0; mm < 2; ++mm)
#pragma unroll
        for (int nn = 0; nn < 2; ++nn) {
            const int col = n0 + wc * 64 + nn * 32 + (l & 31);
#pragma unroll
            for (int q = 0; q < 16; ++q) {
                int row = m0 + wr * 64 + mm * 32 + (q & 3) + 8 * (q >> 2) + 4 * (l >> 5);
                slice[(size_t)row * N + col] = acc[mm][nn][q];
            }
        }
}

// sum Z split-K slices + tanh. MODE 0: write fp32. MODE 1: write split bf16.
template<int MODE>
__global__ __launch_bounds__(256)
void reduce_tanh(const float* __restrict__ par, int n, int Z,
                 float* __restrict__ outF,
                 ushort* __restrict__ hi, ushort* __restrict__ lo) {
    int i = (blockIdx.x * 256 + threadIdx.x) * 4;
    if (i >= n) return;
    float4 s = ld4(par + i);
    for (int z = 1; z < Z; ++z) {
        float4 v = ld4(par + (size_t)z * n + i);
        s.x += v.x; s.y += v.y; s.z += v.z; s.w += v.w;
    }
    s.x = tanhf(s.x); s.y = tanhf(s.y); s.z = tanhf(s.z); s.w = tanhf(s.w);
    if (MODE == 0) {
        *(float4*)(outF + i) = s;
    } else {
        uint2 hp, lp;
        split2(s.x, s.y, hp.x, lp.x);
        split2(s.z, s.w, hp.y, lp.y);
        *(uint2*)(hi + i) = hp;
        *(uint2*)(lo + i) = lp;
    }
}

__global__ __launch_bounds__(256)
void split_x(const float* __restrict__ x, ushort* __restrict__ hi,
             ushort* __restrict__ lo, int n) {
    int i = (blockIdx.x * 256 + threadIdx.x) * 4;
    if (i >= n) return;
    float4 v = ld4(x + i);
    uint2 hp, lp;
    split2(v.x, v.y, hp.x, lp.x);
    split2(v.z, v.w, hp.y, lp.y);
    *(uint2*)(hi + i) = hp;
    *(uint2*)(lo + i) = lp;
}

// Per-node Hebbian params -> SoA (10240 nodes).
__global__ void node_precompute(const float* __restrict__ hebb,
                                const float* __restrict__ x,
                                const ushort* __restrict__ h1hi, const ushort* __restrict__ h1lo,
                                const ushort* __restrict__ h2hi, const ushort* __restrict__ h2lo,
                                const float* __restrict__ y,
                                float* __restrict__ Av, float* __restrict__ Bv,
                                float* __restrict__ Cv, float* __restrict__ Dv,
                                float* __restrict__ Ev) {
    int n = blockIdx.x * blockDim.x + threadIdx.x;
    if (n >= 10240) return;
    float a;
    if (n < 1024)      a = x[n];
    else if (n < 5120) a = as_f((uint)h1hi[n - 1024] << 16) + as_f((uint)h1lo[n - 1024] << 16);
    else if (n < 9216) a = as_f((uint)h2hi[n - 5120] << 16) + as_f((uint)h2lo[n - 5120] << 16);
    else               a = y[n - 9216];
    float p0 = hebb[n * 5 + 0], p1 = hebb[n * 5 + 1], p2 = hebb[n * 5 + 2];
    float p3 = hebb[n * 5 + 3], p4 = hebb[n * 5 + 4];
    Av[n] = p0 * a;
    Bv[n] = p1 * a;
    Cv[n] = (p2 == 1.0f) ? 1.0f : p2 * a;
    Dv[n] = p3;
    Ev[n] = p4;
}

// nW[j,i] = W[j,i] + 0.5*(Ei+Ej)*(Ai + Bj + corr + dec). Streaming.
__global__ __launch_bounds__(256)
void hebb_update(const float* __restrict__ W, float* __restrict__ out,
                 const float* __restrict__ Av, const float* __restrict__ Bv,
                 const float* __restrict__ Cv, const float* __restrict__ Dv,
                 const float* __restrict__ Ev,
                 int pre_off, int post_off, int n_pre) {
    const int segs = n_pre >> 10;
    const int j    = blockIdx.x / segs;
    const int seg  = blockIdx.x % segs;
    const int i0   = (seg << 10) + threadIdx.x * 4;

    const float bj = Bv[post_off + j];
    const float cj = Cv[post_off + j];
    const float dj = Dv[post_off + j];
    const float ej = Ev[post_off + j];
    const bool cj1 = (cj == 1.0f);
    const bool dj1 = (dj == 1.0f);

    const size_t base = (size_t)j * n_pre + i0;
    float4 w  = ld4(W + base);
    float4 ai = ld4(Av + pre_off + i0);
    float4 ci = ld4(Cv + pre_off + i0);
    float4 di = ld4(Dv + pre_off + i0);
    float4 ei = ld4(Ev + pre_off + i0);

    float4 r;
    { float corr = (cj1 && ci.x == 1.0f) ? 0.0f : ci.x * cj;
      float dec  = (dj1 && di.x == 1.0f) ? 0.0f : di.x * dj;
      r.x = w.x + 0.5f * (ei.x + ej) * (ai.x + bj + corr + dec); }
    { float corr = (cj1 && ci.y == 1.0f) ? 0.0f : ci.y * cj;
      float dec  = (dj1 && di.y == 1.0f) ? 0.0f : di.y * dj;
      r.y = w.y + 0.5f * (ei.y + ej) * (ai.y + bj + corr + dec); }
    { float corr = (cj1 && ci.z == 1.0f) ? 0.0f : ci.z * cj;
      float dec  = (dj1 && di.z == 1.0f) ? 0.0f : di.z * dj;
      r.z = w.z + 0.5f * (ei.z + ej) * (ai.z + bj + corr + dec); }
    { float corr = (cj1 && ci.w == 1.0f) ? 0.0f : ci.w * cj;
      float dec  = (dj1 && di.w == 1.0f) ? 0.0f : di.w * dj;
      r.w = w.w + 0.5f * (ei.w + ej) * (ai.w + bj + corr + dec); }
    *(float4*)(out + base) = r;
}

extern "C" void kernel_launch(void* const* d_in, const int* in_sizes, int n_in,
                              void* d_out, int out_size, void* d_ws, size_t ws_size,
                              hipStream_t stream) {
    const float* x    = (const float*)d_in[0];   // [256,1024]
    const float* W1   = (const float*)d_in[1];   // [4096,1024]
    const float* W2   = (const float*)d_in[2];   // [4096,4096]
    const float* W3   = (const float*)d_in[3];   // [1024,4096]
    const float* hebb = (const float*)d_in[4];   // [10240,5]
    float* out = (float*)d_out;

    float* y_out   = out;                        // 262144
    float* nW1_out = out + 262144;
    float* nW2_out = out + 4456448;              // 16777216 floats
    float* nW3_out = out + 21233664;

    // Scratch inside nW2 slice (float offsets; all dead before nW2 written):
    float*  par  = nW2_out;                      // 4,194,304 f32 (16 MB)
    ushort* xhi  = (ushort*)(nW2_out + 4194304); // 262144 bf16
    ushort* xlo  = (ushort*)(nW2_out + 4325376);
    ushort* h1hi = (ushort*)(nW2_out + 4456448); // 1,048,576 bf16
    ushort* h1lo = (ushort*)(nW2_out + 4980736);
    ushort* h2hi = (ushort*)(nW2_out + 5505024);
    ushort* h2lo = (ushort*)(nW2_out + 6029312); // ends at 6,553,600 < 16.7M

    // d_ws: node vectors (must survive the nW2 overwrite). 200 KB.
    float* Av = (float*)d_ws;
    float* Bv = Av + 10240;
    float* Cv = Bv + 10240;
    float* Dv = Cv + 10240;
    float* Ev = Dv + 10240;

    split_x<<<256, 256, 0, stream>>>(x, xhi, xlo, 262144);

    // L1: K=1024, N=4096, split-K 4 (kchunk 256) -> 32x2x4 = 256 blocks
    gemm_split<<<dim3(32, 2, 4), 256, 0, stream>>>(xhi, xlo, W1, par, 4096, 1024, 256);
    reduce_tanh<1><<<1024, 256, 0, stream>>>(par, 1048576, 4, nullptr, h1hi, h1lo);

    // L2: K=4096, N=4096, split-K 4 (kchunk 1024)
    gemm_split<<<dim3(32, 2, 4), 256, 0, stream>>>(h1hi, h1lo, W2, par, 4096, 4096, 1024);
    reduce_tanh<1><<<1024, 256, 0, stream>>>(par, 1048576, 4, nullptr, h2hi, h2lo);

    // L3: K=4096, N=1024, split-K 16 (kchunk 256) -> 8x2x16 = 256 blocks
    gemm_split<<<dim3(8, 2, 16), 256, 0, stream>>>(h2hi, h2lo, W3, par, 1024, 4096, 256);
    reduce_tanh<0><<<256, 256, 0, stream>>>(par, 262144, 16, y_out, nullptr, nullptr);

    node_precompute<<<40, 256, 0, stream>>>(hebb, x, h1hi, h1lo, h2hi, h2lo, y_out,
                                            Av, Bv, Cv, Dv, Ev);

    hebb_update<<<4096, 256, 0, stream>>>(W1, nW1_out, Av, Bv, Cv, Dv, Ev, 0, 1024, 1024);
    hebb_update<<<4096, 256, 0, stream>>>(W3, nW3_out, Av, Bv, Cv, Dv, Ev, 5120, 9216, 4096);
    // nW2 LAST: overwrites the scratch slice.
    hebb_update<<<16384, 256, 0, stream>>>(W2, nW2_out, Av, Bv, Cv, Dv, Ev, 1024, 5120, 4096);
}

// Round 4
// 281.797 us; speedup vs baseline: 1.3554x; 1.3554x over previous
//
#include <hip/hip_runtime.h>
#include <cstddef>

// ---------------------------------------------------------------------------
// NCHL on MI355X. Forward: split-bf16 3-product MFMA GEMMs (no fp32 MFMA on
// CDNA4): a = ahi+alo (bf16 truncation split), ab ≈ ahi*bhi+ahi*blo+alo*bhi.
// m97-style GEMM: A via global_load_lds (async, pre-swizzled source), B
// reg-staged fp32->split-bf16 with one-tile prefetch, 128x128 tile, BK=64,
// split-K sized so every GEMM launches 512 blocks (2 blocks/CU).
// Scratch lives inside the nW2 output slice (dead before nW2 is written);
// d_ws holds only the 200 KB node-param vectors.
// ---------------------------------------------------------------------------

typedef __attribute__((ext_vector_type(8)))  short short8;   // 8 bf16
typedef __attribute__((ext_vector_type(16))) float f32x16;   // 32x32 acc

__device__ __forceinline__ uint  as_u(float f) { return __float_as_uint(f); }
__device__ __forceinline__ float as_f(uint u)  { return __uint_as_float(u); }
__device__ __forceinline__ float4 ld4(const float* p) { return *(const float4*)p; }

// truncation split of (f0,f1) -> packed hi u32 (f0 low half) + packed lo
__device__ __forceinline__ void split2(float f0, float f1, uint& hp, uint& lp) {
    uint u0 = as_u(f0), u1 = as_u(f1);
    uint h0 = u0 & 0xffff0000u, h1 = u1 & 0xffff0000u;
    float l0 = f0 - as_f(h0), l1 = f1 - as_f(h1);
    hp = h1 | (h0 >> 16);
    lp = (as_u(l1) & 0xffff0000u) | (as_u(l0) >> 16);
}

#define BKT 64
#define REG_AHI 0
#define REG_ALO 16384
#define REG_BHI 32768
#define REG_BLO 49152

// byte offset inside a 128-row x 128-byte region; kbyte multiple of 16
__device__ __forceinline__ int swz(int row, int kbyte) {
    return row * 128 + (kbyte ^ ((row & 7) << 4));
}

#define GLL16(src, dst)                                                        \
    __builtin_amdgcn_global_load_lds(                                          \
        (const __attribute__((address_space(1))) void*)(src),                  \
        (__attribute__((address_space(3))) void*)(dst), 16, 0, 0)

// par[z][m,n] = sum_{k in chunk z} A[m,k]*W[n,k].  A presplit bf16 hi/lo.
__global__ __launch_bounds__(256, 2)
void gemm_split(const ushort* __restrict__ Ahi, const ushort* __restrict__ Alo,
                const float* __restrict__ W, float* __restrict__ par,
                int N, int K, int kchunk) {
    __shared__ uint4 lds4[4096];                 // 64 KB
    char* lds = (char*)lds4;

    const int tid = threadIdx.x;
    const int l   = tid & 63;
    const int wid = tid >> 6;
    const int wr  = wid >> 1, wc = wid & 1;      // 2x2 wave grid of 64x64
    const int m0  = blockIdx.y * 128;
    const int n0  = blockIdx.x * 128;
    const int kb0 = blockIdx.z * kchunk;
    const int T   = kchunk / BKT;

    // ---- A via global_load_lds: linear LDS dest, inverse-swizzled source.
    // wave w covers rows [w*32, w*32+32); instr i covers 8 rows (1 KB).
    // dest byte d = w*4096 + i*1024 + lane*16  ->  row = w*32+i*8+(l>>3),
    // src k-offset (elements) = ((l&7) ^ (l>>3)) * 8   (XOR within 128B row).
    const int a_row0 = m0 + wid * 32 + (l >> 3);
    const int a_kel  = ((l & 7) ^ (l >> 3)) << 3;
    const int a_dst0 = wid * 4096 + (l >> 3) * 128; // lane*16 = (l>>3)*128 + (l&7)*16
    // note: lds dest passed to GLL16 must be the wave-uniform lane-0 base:
    const int a_dstw = wid * 4096;

    // ---- B staging: thread covers W row (n0 + tid/2), k-half (tid&1)*32.
    const int br = tid >> 1;
    const int bk = (tid & 1) * 32;
    const float* wp0 = W + (size_t)(n0 + br) * K + kb0 + bk;
    float4 bReg[8];

    auto loadB = [&](int t) {
        const float* wp = wp0 + t * BKT;
#pragma unroll
        for (int i = 0; i < 8; ++i) bReg[i] = ld4(wp + 4 * i);
    };
    auto gllA = [&](int t) {
        const size_t kb = kb0 + t * BKT;
        const ushort* sh = Ahi + (size_t)a_row0 * K + kb + a_kel;
        const ushort* sl = Alo + (size_t)a_row0 * K + kb + a_kel;
#pragma unroll
        for (int i = 0; i < 4; ++i) {
            GLL16(sh + (size_t)(i * 8) * K, lds + REG_AHI + a_dstw + i * 1024);
            GLL16(sl + (size_t)(i * 8) * K, lds + REG_ALO + a_dstw + i * 1024);
        }
    };
    auto writeB = [&]() {
#pragma unroll
        for (int i = 0; i < 4; ++i) {
            float4 fa = bReg[2 * i], fb = bReg[2 * i + 1];
            uint4 hp, lp;
            split2(fa.x, fa.y, hp.x, lp.x);
            split2(fa.z, fa.w, hp.y, lp.y);
            split2(fb.x, fb.y, hp.z, lp.z);
            split2(fb.z, fb.w, hp.w, lp.w);
            int kby = (bk + 8 * i) * 2;
            *(uint4*)(lds + REG_BHI + swz(br, kby)) = hp;
            *(uint4*)(lds + REG_BLO + swz(br, kby)) = lp;
        }
    };

    f32x16 acc[2][2] = {};
    const int arow = wr * 64 + (l & 31);
    const int brow = wc * 64 + (l & 31);
    const int kfr  = 16 * (l >> 5);

    loadB(0);
    for (int t = 0; t < T; ++t) {
        __syncthreads();            // prev tile's readers done; drains bReg loads
        gllA(t);                    // async global->LDS (drained by next barrier)
        writeB();                   // convert + ds_write current B
        __syncthreads();            // A landed + B visible
        if (t + 1 < T) loadB(t + 1);// prefetch; waited at NEXT tile's barrier
#pragma unroll
        for (int kk = 0; kk < 4; ++kk) {
            const int kby = kk * 32 + kfr;
            short8 ah0 = *(const short8*)(lds + REG_AHI + swz(arow,      kby));
            short8 ah1 = *(const short8*)(lds + REG_AHI + swz(arow + 32, kby));
            short8 al0 = *(const short8*)(lds + REG_ALO + swz(arow,      kby));
            short8 al1 = *(const short8*)(lds + REG_ALO + swz(arow + 32, kby));
            short8 bh0 = *(const short8*)(lds + REG_BHI + swz(brow,      kby));
            short8 bh1 = *(const short8*)(lds + REG_BHI + swz(brow + 32, kby));
            short8 bl0 = *(const short8*)(lds + REG_BLO + swz(brow,      kby));
            short8 bl1 = *(const short8*)(lds + REG_BLO + swz(brow + 32, kby));
            acc[0][0] = __builtin_amdgcn_mfma_f32_32x32x16_bf16(ah0, bh0, acc[0][0], 0, 0, 0);
            acc[0][1] = __builtin_amdgcn_mfma_f32_32x32x16_bf16(ah0, bh1, acc[0][1], 0, 0, 0);
            acc[1][0] = __builtin_amdgcn_mfma_f32_32x32x16_bf16(ah1, bh0, acc[1][0], 0, 0, 0);
            acc[1][1] = __builtin_amdgcn_mfma_f32_32x32x16_bf16(ah1, bh1, acc[1][1], 0, 0, 0);
            acc[0][0] = __builtin_amdgcn_mfma_f32_32x32x16_bf16(ah0, bl0, acc[0][0], 0, 0, 0);
            acc[0][1] = __builtin_amdgcn_mfma_f32_32x32x16_bf16(ah0, bl1, acc[0][1], 0, 0, 0);
            acc[1][0] = __builtin_amdgcn_mfma_f32_32x32x16_bf16(ah1, bl0, acc[1][0], 0, 0, 0);
            acc[1][1] = __builtin_amdgcn_mfma_f32_32x32x16_bf16(ah1, bl1, acc[1][1], 0, 0, 0);
            acc[0][0] = __builtin_amdgcn_mfma_f32_32x32x16_bf16(al0, bh0, acc[0][0], 0, 0, 0);
            acc[0][1] = __builtin_amdgcn_mfma_f32_32x32x16_bf16(al0, bh1, acc[0][1], 0, 0, 0);
            acc[1][0] = __builtin_amdgcn_mfma_f32_32x32x16_bf16(al1, bh0, acc[1][0], 0, 0, 0);
            acc[1][1] = __builtin_amdgcn_mfma_f32_32x32x16_bf16(al1, bh1, acc[1][1], 0, 0, 0);
        }
    }
    (void)a_dst0;

    // C/D layout: col=lane&31, row=(q&3)+8*(q>>2)+4*(lane>>5)   [m74/m101]
    float* slice = par + (size_t)blockIdx.z * 256 * N;
#pragma unroll
    for (int mm = 0; mm < 2; ++mm)
#pragma unroll
        for (int nn = 0; nn < 2; ++nn) {
            const int col = n0 + wc * 64 + nn * 32 + (l & 31);
#pragma unroll
            for (int q = 0; q < 16; ++q) {
                int row = m0 + wr * 64 + mm * 32 + (q & 3) + 8 * (q >> 2) + 4 * (l >> 5);
                slice[(size_t)row * N + col] = acc[mm][nn][q];
            }
        }
}

// sum Z split-K slices + tanh. MODE 0: fp32 out. MODE 1: split-bf16 out.
template<int MODE, int Z>
__global__ __launch_bounds__(256)
void reduce_tanh(const float* __restrict__ par, int n,
                 float* __restrict__ outF,
                 ushort* __restrict__ hi, ushort* __restrict__ lo) {
    int i = (blockIdx.x * 256 + threadIdx.x) * 4;
    if (i >= n) return;
    float4 s = ld4(par + i);
#pragma unroll
    for (int z = 1; z < Z; ++z) {
        float4 v = ld4(par + (size_t)z * n + i);
        s.x += v.x; s.y += v.y; s.z += v.z; s.w += v.w;
    }
    s.x = tanhf(s.x); s.y = tanhf(s.y); s.z = tanhf(s.z); s.w = tanhf(s.w);
    if (MODE == 0) {
        *(float4*)(outF + i) = s;
    } else {
        uint2 hp, lp;
        split2(s.x, s.y, hp.x, lp.x);
        split2(s.z, s.w, hp.y, lp.y);
        *(uint2*)(hi + i) = hp;
        *(uint2*)(lo + i) = lp;
    }
}

__global__ __launch_bounds__(256)
void split_x(const float* __restrict__ x, ushort* __restrict__ hi,
             ushort* __restrict__ lo, int n) {
    int i = (blockIdx.x * 256 + threadIdx.x) * 4;
    if (i >= n) return;
    float4 v = ld4(x + i);
    uint2 hp, lp;
    split2(v.x, v.y, hp.x, lp.x);
    split2(v.z, v.w, hp.y, lp.y);
    *(uint2*)(hi + i) = hp;
    *(uint2*)(lo + i) = lp;
}

__global__ void node_precompute(const float* __restrict__ hebb,
                                const float* __restrict__ x,
                                const ushort* __restrict__ h1hi, const ushort* __restrict__ h1lo,
                                const ushort* __restrict__ h2hi, const ushort* __restrict__ h2lo,
                                const float* __restrict__ y,
                                float* __restrict__ Av, float* __restrict__ Bv,
                                float* __restrict__ Cv, float* __restrict__ Dv,
                                float* __restrict__ Ev) {
    int n = blockIdx.x * blockDim.x + threadIdx.x;
    if (n >= 10240) return;
    float a;
    if (n < 1024)      a = x[n];
    else if (n < 5120) a = as_f((uint)h1hi[n - 1024] << 16) + as_f((uint)h1lo[n - 1024] << 16);
    else if (n < 9216) a = as_f((uint)h2hi[n - 5120] << 16) + as_f((uint)h2lo[n - 5120] << 16);
    else               a = y[n - 9216];
    float p0 = hebb[n * 5 + 0], p1 = hebb[n * 5 + 1], p2 = hebb[n * 5 + 2];
    float p3 = hebb[n * 5 + 3], p4 = hebb[n * 5 + 4];
    Av[n] = p0 * a;
    Bv[n] = p1 * a;
    Cv[n] = (p2 == 1.0f) ? 1.0f : p2 * a;
    Dv[n] = p3;
    Ev[n] = p4;
}

__global__ __launch_bounds__(256)
void hebb_update(const float* __restrict__ W, float* __restrict__ out,
                 const float* __restrict__ Av, const float* __restrict__ Bv,
                 const float* __restrict__ Cv, const float* __restrict__ Dv,
                 const float* __restrict__ Ev,
                 int pre_off, int post_off, int n_pre) {
    const int segs = n_pre >> 10;
    const int j    = blockIdx.x / segs;
    const int seg  = blockIdx.x % segs;
    const int i0   = (seg << 10) + threadIdx.x * 4;

    const float bj = Bv[post_off + j];
    const float cj = Cv[post_off + j];
    const float dj = Dv[post_off + j];
    const float ej = Ev[post_off + j];
    const bool cj1 = (cj == 1.0f);
    const bool dj1 = (dj == 1.0f);

    const size_t base = (size_t)j * n_pre + i0;
    float4 w  = ld4(W + base);
    float4 ai = ld4(Av + pre_off + i0);
    float4 ci = ld4(Cv + pre_off + i0);
    float4 di = ld4(Dv + pre_off + i0);
    float4 ei = ld4(Ev + pre_off + i0);

    float4 r;
    { float corr = (cj1 && ci.x == 1.0f) ? 0.0f : ci.x * cj;
      float dec  = (dj1 && di.x == 1.0f) ? 0.0f : di.x * dj;
      r.x = w.x + 0.5f * (ei.x + ej) * (ai.x + bj + corr + dec); }
    { float corr = (cj1 && ci.y == 1.0f) ? 0.0f : ci.y * cj;
      float dec  = (dj1 && di.y == 1.0f) ? 0.0f : di.y * dj;
      r.y = w.y + 0.5f * (ei.y + ej) * (ai.y + bj + corr + dec); }
    { float corr = (cj1 && ci.z == 1.0f) ? 0.0f : ci.z * cj;
      float dec  = (dj1 && di.z == 1.0f) ? 0.0f : di.z * dj;
      r.z = w.z + 0.5f * (ei.z + ej) * (ai.z + bj + corr + dec); }
    { float corr = (cj1 && ci.w == 1.0f) ? 0.0f : ci.w * cj;
      float dec  = (dj1 && di.w == 1.0f) ? 0.0f : di.w * dj;
      r.w = w.w + 0.5f * (ei.w + ej) * (ai.w + bj + corr + dec); }
    *(float4*)(out + base) = r;
}

extern "C" void kernel_launch(void* const* d_in, const int* in_sizes, int n_in,
                              void* d_out, int out_size, void* d_ws, size_t ws_size,
                              hipStream_t stream) {
    const float* x    = (const float*)d_in[0];   // [256,1024]
    const float* W1   = (const float*)d_in[1];   // [4096,1024]
    const float* W2   = (const float*)d_in[2];   // [4096,4096]
    const float* W3   = (const float*)d_in[3];   // [1024,4096]
    const float* hebb = (const float*)d_in[4];   // [10240,5]
    float* out = (float*)d_out;

    float* y_out   = out;                        // 262144
    float* nW1_out = out + 262144;
    float* nW2_out = out + 4456448;              // 16777216 floats
    float* nW3_out = out + 21233664;

    // Scratch inside nW2 slice (all dead before nW2 is written):
    float*  par  = nW2_out;                      // 8 * 1,048,576 f32 (32 MB)
    ushort* xhi  = (ushort*)(nW2_out + 8388608); // 262144 bf16
    ushort* xlo  = xhi + 262144;
    ushort* h1hi = xlo + 262144;                 // 1,048,576 bf16 each
    ushort* h1lo = h1hi + 1048576;
    ushort* h2hi = h1lo + 1048576;
    ushort* h2lo = h2hi + 1048576;               // ends at 10.75M < 16.7M fl

    float* Av = (float*)d_ws;                    // survive nW2 overwrite
    float* Bv = Av + 10240;
    float* Cv = Bv + 10240;
    float* Dv = Cv + 10240;
    float* Ev = Dv + 10240;

    split_x<<<256, 256, 0, stream>>>(x, xhi, xlo, 262144);

    // L1: K=1024, N=4096, split-K 8 (kchunk 128) -> 32x2x8 = 512 blocks
    gemm_split<<<dim3(32, 2, 8), 256, 0, stream>>>(xhi, xlo, W1, par, 4096, 1024, 128);
    reduce_tanh<1, 8><<<1024, 256, 0, stream>>>(par, 1048576, nullptr, h1hi, h1lo);

    // L2: K=4096, N=4096, split-K 8 (kchunk 512) -> 512 blocks
    gemm_split<<<dim3(32, 2, 8), 256, 0, stream>>>(h1hi, h1lo, W2, par, 4096, 4096, 512);
    reduce_tanh<1, 8><<<1024, 256, 0, stream>>>(par, 1048576, nullptr, h2hi, h2lo);

    // L3: K=4096, N=1024, split-K 32 (kchunk 128) -> 8x2x32 = 512 blocks
    gemm_split<<<dim3(8, 2, 32), 256, 0, stream>>>(h2hi, h2lo, W3, par, 1024, 4096, 128);
    reduce_tanh<0, 32><<<256, 256, 0, stream>>>(par, 262144, y_out, nullptr, nullptr);

    node_precompute<<<40, 256, 0, stream>>>(hebb, x, h1hi, h1lo, h2hi, h2lo, y_out,
                                            Av, Bv, Cv, Dv, Ev);

    hebb_update<<<4096, 256, 0, stream>>>(W1, nW1_out, Av, Bv, Cv, Dv, Ev, 0, 1024, 1024);
    hebb_update<<<4096, 256, 0, stream>>>(W3, nW3_out, Av, Bv, Cv, Dv, Ev, 5120, 9216, 4096);
    // nW2 LAST: overwrites the scratch slice.
    hebb_update<<<16384, 256, 0, stream>>>(W2, nW2_out, Av, Bv, Cv, Dv, Ev, 1024, 5120, 4096);
}

// Round 6
// 277.925 us; speedup vs baseline: 1.3743x; 1.0139x over previous
//
#include <hip/hip_runtime.h>
#include <cstddef>

// ---------------------------------------------------------------------------
// NCHL on MI355X. Forward: split-bf16 3-product MFMA GEMMs (no fp32 MFMA on
// CDNA4): a = ahi+alo (bf16 truncation split), ab ≈ ahi*bhi+ahi*blo+alo*bhi.
// GEMM: 128x128 tile, BK=64, FULL double-buffered LDS (128 KB, 1 block/CU),
// one barrier per K-tile; A via global_load_lds (pre-swizzled source), B
// reg-staged fp32->split-bf16 with 2-tile-deep prefetch (named reg sets).
// Split-K z=4 (z=16 for L3) so grid = 256 blocks. Hebbian updates fused into
// one streaming kernel. Scratch lives inside the nW2 output slice; d_ws holds
// only the 200 KB node-param vectors.
// ---------------------------------------------------------------------------

typedef __attribute__((ext_vector_type(8)))  short short8;   // 8 bf16
typedef __attribute__((ext_vector_type(16))) float f32x16;   // 32x32 acc

__device__ __forceinline__ uint  as_u(float f) { return __float_as_uint(f); }
__device__ __forceinline__ float as_f(uint u)  { return __uint_as_float(u); }
__device__ __forceinline__ float4 ld4(const float* p) { return *(const float4*)p; }

// truncation split of (f0,f1) -> packed hi u32 (f0 low half) + packed lo
__device__ __forceinline__ void split2(float f0, float f1, uint& hp, uint& lp) {
    uint u0 = as_u(f0), u1 = as_u(f1);
    uint h0 = u0 & 0xffff0000u, h1 = u1 & 0xffff0000u;
    float l0 = f0 - as_f(h0), l1 = f1 - as_f(h1);
    hp = h1 | (h0 >> 16);
    lp = (as_u(l1) & 0xffff0000u) | (as_u(l0) >> 16);
}

#define BKT 64
#define REG_AHI 0
#define REG_ALO 16384
#define REG_BHI 32768
#define REG_BLO 49152
#define BUFSZ   65536

// byte offset inside a 128-row x 128-byte region; kbyte multiple of 16
__device__ __forceinline__ int swz(int row, int kbyte) {
    return row * 128 + (kbyte ^ ((row & 7) << 4));
}

#define GLL16(src, dst)                                                        \
    __builtin_amdgcn_global_load_lds(                                          \
        (const __attribute__((address_space(1))) void*)(src),                  \
        (__attribute__((address_space(3))) void*)(dst), 16, 0, 0)

// par[z][m,n] = sum_{k in chunk z} A[m,k]*W[n,k].  A presplit bf16 hi/lo.
__global__ __launch_bounds__(256, 1)
void gemm_split(const ushort* __restrict__ Ahi, const ushort* __restrict__ Alo,
                const float* __restrict__ W, float* __restrict__ par,
                int N, int K, int kchunk) {
    __shared__ __align__(16) char lds[2 * BUFSZ];   // 128 KB double buffer

    const int tid = threadIdx.x;
    const int l   = tid & 63;
    const int wid = tid >> 6;
    const int wr  = wid >> 1, wc = wid & 1;      // 2x2 wave grid of 64x64
    const int m0  = blockIdx.y * 128;
    const int n0  = blockIdx.x * 128;
    const int kb0 = blockIdx.z * kchunk;
    const int T   = kchunk / BKT;                // always even (>= 4)

    // ---- A via global_load_lds: linear LDS dest, inverse-swizzled source.
    // dest byte = wid*4096 + i*1024 + lane*16 -> row = wid*32+i*8+(l>>3);
    // source k-offset = ((l&7) ^ (l>>3)) * 8 elements (XOR within 128B row).
    const int a_row0 = m0 + wid * 32 + (l >> 3);
    const int a_kel  = ((l & 7) ^ (l >> 3)) << 3;
    const int a_dstw = wid * 4096;               // wave-uniform base

    // ---- B staging: thread covers W row n0+(tid>>1), k-half (tid&1)*32.
    const int br = tid >> 1;
    const int bk = (tid & 1) * 32;
    const float* wp0 = W + (size_t)(n0 + br) * K + kb0 + bk;

    float4 bRA[8], bRB[8];                       // two named prefetch sets

#define LOADB(dst, t)                                                          \
    { const float* wp = wp0 + (t) * BKT;                                       \
      _Pragma("unroll") for (int i = 0; i < 8; ++i) dst[i] = ld4(wp + 4 * i); }

#define WRITEB(srcreg, buf)                                                    \
    { _Pragma("unroll") for (int i = 0; i < 4; ++i) {                          \
        float4 fa = srcreg[2 * i], fb = srcreg[2 * i + 1];                     \
        uint4 hp, lp;                                                          \
        split2(fa.x, fa.y, hp.x, lp.x);                                        \
        split2(fa.z, fa.w, hp.y, lp.y);                                        \
        split2(fb.x, fb.y, hp.z, lp.z);                                        \
        split2(fb.z, fb.w, hp.w, lp.w);                                        \
        int kby = (bk + 8 * i) * 2;                                            \
        *(uint4*)((buf) + REG_BHI + swz(br, kby)) = hp;                        \
        *(uint4*)((buf) + REG_BLO + swz(br, kby)) = lp; } }

#define GLLA(t, buf)                                                           \
    { const size_t kb_ = kb0 + (size_t)(t) * BKT;                              \
      const ushort* sh = Ahi + (size_t)a_row0 * K + kb_ + a_kel;               \
      const ushort* sl = Alo + (size_t)a_row0 * K + kb_ + a_kel;               \
      _Pragma("unroll") for (int i = 0; i < 4; ++i) {                          \
        GLL16(sh + (size_t)(i * 8) * K, (buf) + REG_AHI + a_dstw + i * 1024);  \
        GLL16(sl + (size_t)(i * 8) * K, (buf) + REG_ALO + a_dstw + i * 1024); } }

    f32x16 acc[2][2] = {};
    const int arow = wr * 64 + (l & 31);
    const int brow = wc * 64 + (l & 31);
    const int kfr  = 16 * (l >> 5);

#define MFMA_PHASE(buf)                                                        \
    { _Pragma("unroll") for (int kk = 0; kk < 4; ++kk) {                       \
        const int kby = kk * 32 + kfr;                                         \
        short8 ah0 = *(const short8*)((buf) + REG_AHI + swz(arow,      kby));  \
        short8 ah1 = *(const short8*)((buf) + REG_AHI + swz(arow + 32, kby));  \
        short8 al0 = *(const short8*)((buf) + REG_ALO + swz(arow,      kby));  \
        short8 al1 = *(const short8*)((buf) + REG_ALO + swz(arow + 32, kby));  \
        short8 bh0 = *(const short8*)((buf) + REG_BHI + swz(brow,      kby));  \
        short8 bh1 = *(const short8*)((buf) + REG_BHI + swz(brow + 32, kby));  \
        short8 bl0 = *(const short8*)((buf) + REG_BLO + swz(brow,      kby));  \
        short8 bl1 = *(const short8*)((buf) + REG_BLO + swz(brow + 32, kby));  \
        acc[0][0] = __builtin_amdgcn_mfma_f32_32x32x16_bf16(ah0, bh0, acc[0][0], 0, 0, 0); \
        acc[0][1] = __builtin_amdgcn_mfma_f32_32x32x16_bf16(ah0, bh1, acc[0][1], 0, 0, 0); \
        acc[1][0] = __builtin_amdgcn_mfma_f32_32x32x16_bf16(ah1, bh0, acc[1][0], 0, 0, 0); \
        acc[1][1] = __builtin_amdgcn_mfma_f32_32x32x16_bf16(ah1, bh1, acc[1][1], 0, 0, 0); \
        acc[0][0] = __builtin_amdgcn_mfma_f32_32x32x16_bf16(ah0, bl0, acc[0][0], 0, 0, 0); \
        acc[0][1] = __builtin_amdgcn_mfma_f32_32x32x16_bf16(ah0, bl1, acc[0][1], 0, 0, 0); \
        acc[1][0] = __builtin_amdgcn_mfma_f32_32x32x16_bf16(ah1, bl0, acc[1][0], 0, 0, 0); \
        acc[1][1] = __builtin_amdgcn_mfma_f32_32x32x16_bf16(ah1, bl1, acc[1][1], 0, 0, 0); \
        acc[0][0] = __builtin_amdgcn_mfma_f32_32x32x16_bf16(al0, bh0, acc[0][0], 0, 0, 0); \
        acc[0][1] = __builtin_amdgcn_mfma_f32_32x32x16_bf16(al0, bh1, acc[0][1], 0, 0, 0); \
        acc[1][0] = __builtin_amdgcn_mfma_f32_32x32x16_bf16(al1, bh0, acc[1][0], 0, 0, 0); \
        acc[1][1] = __builtin_amdgcn_mfma_f32_32x32x16_bf16(al1, bh1, acc[1][1], 0, 0, 0); } }

    char* buf0 = lds;
    char* buf1 = lds + BUFSZ;

    // prologue: fill buf0 (tile 0), start B(1) prefetch
    LOADB(bRA, 0);
    WRITEB(bRA, buf0);          // compiler waits vmcnt for bRA here
    GLLA(0, buf0);
    LOADB(bRB, 1);
    __syncthreads();            // buf0 ready (gllA drained); bRB in flight

    for (int t = 0; t < T; t += 2) {
        // ---- even tile t: compute buf0, fill buf1 (tile t+1)
        if (t + 1 < T) GLLA(t + 1, buf1);
        if (t + 2 < T) LOADB(bRA, t + 2);   // issued BEFORE compute -> covered
        MFMA_PHASE(buf0);
        if (t + 1 < T) {
            WRITEB(bRB, buf1);              // bRB issued a full tile ago
            __syncthreads();                // buf1 ready; drains prefetches
        }
        // ---- odd tile t+1: compute buf1, fill buf0 (tile t+2)
        if (t + 1 < T) {
            if (t + 2 < T) GLLA(t + 2, buf0);
            if (t + 3 < T) LOADB(bRB, t + 3);
            MFMA_PHASE(buf1);
            if (t + 2 < T) {
                WRITEB(bRA, buf0);
                __syncthreads();
            }
        }
    }

    // C/D layout: col=lane&31, row=(q&3)+8*(q>>2)+4*(lane>>5)   [m74/m101]
    float* slice = par + (size_t)blockIdx.z * 256 * N;
#pragma unroll
    for (int mm = 0; mm < 2; ++mm)
#pragma unroll
        for (int nn = 0; nn < 2; ++nn) {
            const int col = n0 + wc * 64 + nn * 32 + (l & 31);
#pragma unroll
            for (int q = 0; q < 16; ++q) {
                int row = m0 + wr * 64 + mm * 32 + (q & 3) + 8 * (q >> 2) + 4 * (l >> 5);
                slice[(size_t)row * N + col] = acc[mm][nn][q];
            }
        }
}

// sum Z split-K slices + tanh. MODE 0: fp32 out. MODE 1: split-bf16 out.
template<int MODE, int Z>
__global__ __launch_bounds__(256)
void reduce_tanh(const float* __restrict__ par, int n,
                 float* __restrict__ outF,
                 ushort* __restrict__ hi, ushort* __restrict__ lo) {
    int i = (blockIdx.x * 256 + threadIdx.x) * 4;
    if (i >= n) return;
    float4 s = ld4(par + i);
#pragma unroll
    for (int z = 1; z < Z; ++z) {
        float4 v = ld4(par + (size_t)z * n + i);
        s.x += v.x; s.y += v.y; s.z += v.z; s.w += v.w;
    }
    s.x = tanhf(s.x); s.y = tanhf(s.y); s.z = tanhf(s.z); s.w = tanhf(s.w);
    if (MODE == 0) {
        *(float4*)(outF + i) = s;
    } else {
        uint2 hp, lp;
        split2(s.x, s.y, hp.x, lp.x);
        split2(s.z, s.w, hp.y, lp.y);
        *(uint2*)(hi + i) = hp;
        *(uint2*)(lo + i) = lp;
    }
}

__global__ __launch_bounds__(256)
void split_x(const float* __restrict__ x, ushort* __restrict__ hi,
             ushort* __restrict__ lo, int n) {
    int i = (blockIdx.x * 256 + threadIdx.x) * 4;
    if (i >= n) return;
    float4 v = ld4(x + i);
    uint2 hp, lp;
    split2(v.x, v.y, hp.x, lp.x);
    split2(v.z, v.w, hp.y, lp.y);
    *(uint2*)(hi + i) = hp;
    *(uint2*)(lo + i) = lp;
}

__global__ void node_precompute(const float* __restrict__ hebb,
                                const float* __restrict__ x,
                                const ushort* __restrict__ h1hi, const ushort* __restrict__ h1lo,
                                const ushort* __restrict__ h2hi, const ushort* __restrict__ h2lo,
                                const float* __restrict__ y,
                                float* __restrict__ Av, float* __restrict__ Bv,
                                float* __restrict__ Cv, float* __restrict__ Dv,
                                float* __restrict__ Ev) {
    int n = blockIdx.x * blockDim.x + threadIdx.x;
    if (n >= 10240) return;
    float a;
    if (n < 1024)      a = x[n];
    else if (n < 5120) a = as_f((uint)h1hi[n - 1024] << 16) + as_f((uint)h1lo[n - 1024] << 16);
    else if (n < 9216) a = as_f((uint)h2hi[n - 5120] << 16) + as_f((uint)h2lo[n - 5120] << 16);
    else               a = y[n - 9216];
    float p0 = hebb[n * 5 + 0], p1 = hebb[n * 5 + 1], p2 = hebb[n * 5 + 2];
    float p3 = hebb[n * 5 + 3], p4 = hebb[n * 5 + 4];
    Av[n] = p0 * a;
    Bv[n] = p1 * a;
    Cv[n] = (p2 == 1.0f) ? 1.0f : p2 * a;
    Dv[n] = p3;
    Ev[n] = p4;
}

// All three Hebbian updates in one streaming kernel. Safe in any block order:
// scratch (inside nW2 slice) is dead once node_precompute has run.
// blocks [0,4096): W1; [4096,20480): W2; [20480,24576): W3.
__global__ __launch_bounds__(256)
void hebb_fused(const float* __restrict__ W1, const float* __restrict__ W2,
                const float* __restrict__ W3,
                float* __restrict__ o1, float* __restrict__ o2, float* __restrict__ o3,
                const float* __restrict__ Av, const float* __restrict__ Bv,
                const float* __restrict__ Cv, const float* __restrict__ Dv,
                const float* __restrict__ Ev) {
    const int bid = blockIdx.x;
    const float* W; float* out; int pre_off, post_off, n_pre, j, seg;
    if (bid < 4096) {
        W = W1; out = o1; pre_off = 0;    post_off = 1024; n_pre = 1024;
        j = bid; seg = 0;
    } else if (bid < 20480) {
        int b = bid - 4096;
        W = W2; out = o2; pre_off = 1024; post_off = 5120; n_pre = 4096;
        j = b >> 2; seg = b & 3;
    } else {
        int b = bid - 20480;
        W = W3; out = o3; pre_off = 5120; post_off = 9216; n_pre = 4096;
        j = b >> 2; seg = b & 3;
    }
    const int i0 = (seg << 10) + threadIdx.x * 4;

    const float bj = Bv[post_off + j];
    const float cj = Cv[post_off + j];
    const float dj = Dv[post_off + j];
    const float ej = Ev[post_off + j];
    const bool cj1 = (cj == 1.0f);
    const bool dj1 = (dj == 1.0f);

    const size_t base = (size_t)j * n_pre + i0;
    float4 w  = ld4(W + base);
    float4 ai = ld4(Av + pre_off + i0);
    float4 ci = ld4(Cv + pre_off + i0);
    float4 di = ld4(Dv + pre_off + i0);
    float4 ei = ld4(Ev + pre_off + i0);

    float4 r;
    { float corr = (cj1 && ci.x == 1.0f) ? 0.0f : ci.x * cj;
      float dec  = (dj1 && di.x == 1.0f) ? 0.0f : di.x * dj;
      r.x = w.x + 0.5f * (ei.x + ej) * (ai.x + bj + corr + dec); }
    { float corr = (cj1 && ci.y == 1.0f) ? 0.0f : ci.y * cj;
      float dec  = (dj1 && di.y == 1.0f) ? 0.0f : di.y * dj;
      r.y = w.y + 0.5f * (ei.y + ej) * (ai.y + bj + corr + dec); }
    { float corr = (cj1 && ci.z == 1.0f) ? 0.0f : ci.z * cj;
      float dec  = (dj1 && di.z == 1.0f) ? 0.0f : di.z * dj;
      r.z = w.z + 0.5f * (ei.z + ej) * (ai.z + bj + corr + dec); }
    { float corr = (cj1 && ci.w == 1.0f) ? 0.0f : ci.w * cj;
      float dec  = (dj1 && di.w == 1.0f) ? 0.0f : di.w * dj;
      r.w = w.w + 0.5f * (ei.w + ej) * (ai.w + bj + corr + dec); }
    *(float4*)(out + base) = r;
}

extern "C" void kernel_launch(void* const* d_in, const int* in_sizes, int n_in,
                              void* d_out, int out_size, void* d_ws, size_t ws_size,
                              hipStream_t stream) {
    const float* x    = (const float*)d_in[0];   // [256,1024]
    const float* W1   = (const float*)d_in[1];   // [4096,1024]
    const float* W2   = (const float*)d_in[2];   // [4096,4096]
    const float* W3   = (const float*)d_in[3];   // [1024,4096]
    const float* hebb = (const float*)d_in[4];   // [10240,5]
    float* out = (float*)d_out;

    float* y_out   = out;                        // 262144
    float* nW1_out = out + 262144;
    float* nW2_out = out + 4456448;              // 16777216 floats
    float* nW3_out = out + 21233664;

    // Scratch inside nW2 slice (all dead before hebb_fused runs):
    float*  par  = nW2_out;                      // up to 16 * 262144 f32
    ushort* xhi  = (ushort*)(nW2_out + 8388608); // 262144 bf16
    ushort* xlo  = xhi + 262144;
    ushort* h1hi = xlo + 262144;                 // 1,048,576 bf16 each
    ushort* h1lo = h1hi + 1048576;
    ushort* h2hi = h1lo + 1048576;
    ushort* h2lo = h2hi + 1048576;               // ends at 10.75M < 16.7M fl

    float* Av = (float*)d_ws;                    // survive nW2 overwrite
    float* Bv = Av + 10240;
    float* Cv = Bv + 10240;
    float* Dv = Cv + 10240;
    float* Ev = Dv + 10240;

    split_x<<<256, 256, 0, stream>>>(x, xhi, xlo, 262144);

    // L1: K=1024, N=4096, split-K 4 (kchunk 256, T=4) -> 32x2x4 = 256 blocks
    gemm_split<<<dim3(32, 2, 4), 256, 0, stream>>>(xhi, xlo, W1, par, 4096, 1024, 256);
    reduce_tanh<1, 4><<<1024, 256, 0, stream>>>(par, 1048576, nullptr, h1hi, h1lo);

    // L2: K=4096, N=4096, split-K 4 (kchunk 1024, T=16) -> 256 blocks
    gemm_split<<<dim3(32, 2, 4), 256, 0, stream>>>(h1hi, h1lo, W2, par, 4096, 4096, 1024);
    reduce_tanh<1, 4><<<1024, 256, 0, stream>>>(par, 1048576, nullptr, h2hi, h2lo);

    // L3: K=4096, N=1024, split-K 16 (kchunk 256, T=4) -> 8x2x16 = 256 blocks
    gemm_split<<<dim3(8, 2, 16), 256, 0, stream>>>(h2hi, h2lo, W3, par, 1024, 4096, 256);
    reduce_tanh<0, 16><<<256, 256, 0, stream>>>(par, 262144, y_out, nullptr, nullptr);

    node_precompute<<<40, 256, 0, stream>>>(hebb, x, h1hi, h1lo, h2hi, h2lo, y_out,
                                            Av, Bv, Cv, Dv, Ev);

    hebb_fused<<<24576, 256, 0, stream>>>(W1, W2, W3, nW1_out, nW2_out, nW3_out,
                                          Av, Bv, Cv, Dv, Ev);
}